// Round 21
// baseline (101.785 us; speedup 1.0000x reference)
//
#include <hip/hip_runtime.h>
#include <cstdint>

#define HW  128
#define NCH 256
#define NOC 18      // G*K*K
#define PLANE (HW * HW)
#define EPSBN 1e-5f

typedef __attribute__((ext_vector_type(8)))  short bf16x8;
typedef __attribute__((ext_vector_type(16))) float f32x16;

__device__ __forceinline__ unsigned short f2bf(float f) {
    union { float f; uint32_t u; } c; c.f = f;
    uint32_t u = c.u;
    uint32_t r = u + 0x7FFFu + ((u >> 16) & 1u);   // RNE
    return (unsigned short)(r >> 16);
}

__device__ __forceinline__ int4 pack8(const float* v) {
    int4 d;
    d.x = (uint32_t)f2bf(v[0]) | ((uint32_t)f2bf(v[1]) << 16);
    d.y = (uint32_t)f2bf(v[2]) | ((uint32_t)f2bf(v[3]) << 16);
    d.z = (uint32_t)f2bf(v[4]) | ((uint32_t)f2bf(v[5]) << 16);
    d.w = (uint32_t)f2bf(v[6]) | ((uint32_t)f2bf(v[7]) << 16);
    return d;
}

// double-buffered swizzled LDS: [buf(2)][slot(4)][px(130)][ic(16)] bf16
// = 33280 B total. px stride 32 B; XOR px bit2 into byte bit4.
__device__ __forceinline__ int lds_off(int buf, int slot, int px, int ic) {
    int b = ((((buf << 2) + slot) * 130 + px) * 16 + ic) * 2;
    return b ^ (((px >> 2) & 1) << 4);
}

// ------------- Kernel W: pack weights -> wB[tap][ic>>3][oc(32 pad)][ic&7] bf16
__global__ __launch_bounds__(256) void pasa_wprep(
    const float* __restrict__ w, unsigned short* __restrict__ wB)
{
    int idx = blockIdx.x * 256 + threadIdx.x;      // 9*32*32*8 = 73728
    int icl = idx & 7;
    int oc  = (idx >> 3) & 31;
    int icb = (idx >> 8) & 31;
    int tap = idx >> 13;
    int ic  = icb * 8 + icl;
    float v = (oc < NOC) ? w[((size_t)oc * NCH + ic) * 9 + tap] : 0.0f;
    wB[idx] = f2bf(v);
}

// ------------- Kernel A: K-split conv, chunk=16, DEPTH-2 reg prefetch ------
// grid 1024 = 8 n x 2 K-halves x 64 row-pairs; 512 thr = 8 waves, (512,4).
// Two named reg sets (chunk k -> set[k&1]); per iter:
//   SB(0) [9 MFMA on c] SB(0) [pack set(c+1) -> buf^1] [issue set <- c+3] bar
// Issue->consume distance = one full iteration (~500-900 cy) = load latency.
__global__ __launch_bounds__(512, 4) void pasa_conv_part(
    const float* __restrict__ x, const unsigned short* __restrict__ wB,
    float* __restrict__ partial)
{
    __shared__ __align__(16) char lds[2 * 4 * 130 * 16 * 2];   // 33280 B

    int flat = blockIdx.x;                 // [0,1024)
    const int n     = flat & 7;            // XCD owns one image
    const int local = flat >> 3;           // [0,128)
    const int h     = local >> 6;          // K-half
    const int y0    = (local & 63) * 2;

    const int tid  = threadIdx.x;
    const int lane = tid & 63;
    const int wv   = tid >> 6;             // wave 0..7
    const int m    = lane & 31;            // MFMA col (pixel in tile)
    const int hi   = lane >> 5;            // k-half selector

    const int team = tid >> 7;             // 0..3 -> LDS row slot
    const int p128 = tid & 127;            // global px staged by this thread
    int grow;                              // staged row (reflect)
    if      (team == 0) grow = (y0 == 0) ? 1 : y0 - 1;
    else if (team == 1) grow = y0;
    else if (team == 2) grow = y0 + 1;
    else                grow = (y0 + 1 == HW - 1) ? HW - 2 : y0 + 2;

    const float* xrow = x + (size_t)n * NCH * PLANE
                      + (size_t)(h * 128) * PLANE + (size_t)grow * HW;

    const int out_row = wv >> 2;
    const int px_tile = (wv & 3) * 32;

    f32x16 acc;
    #pragma unroll
    for (int i = 0; i < 16; ++i) acc[i] = 0.0f;

    float sA[16], sB[16];   // set1 = sA (odd chunks), set0 = sB (even chunks)

    // ---- prologue ----
    {   // stage chunk 0 directly into buf 0
        float t0[8], t1[8];
        #pragma unroll
        for (int i = 0; i < 8; ++i) t0[i] = xrow[(size_t)(i)     * PLANE + p128];
        #pragma unroll
        for (int i = 0; i < 8; ++i) t1[i] = xrow[(size_t)(8 + i) * PLANE + p128];
        int4 d0 = pack8(t0), d1 = pack8(t1);
        *(int4*)(lds + lds_off(0, team, p128 + 1, 0)) = d0;
        *(int4*)(lds + lds_off(0, team, p128 + 1, 8)) = d1;
        if (p128 == 1) {
            *(int4*)(lds + lds_off(0, team, 0, 0)) = d0;
            *(int4*)(lds + lds_off(0, team, 0, 8)) = d1;
        }
        if (p128 == 126) {
            *(int4*)(lds + lds_off(0, team, 129, 0)) = d0;
            *(int4*)(lds + lds_off(0, team, 129, 8)) = d1;
        }
    }
    // issue chunk 1 -> sA, chunk 2 -> sB (in flight across the barrier)
    #pragma unroll
    for (int i = 0; i < 16; ++i) sA[i] = xrow[(size_t)(16 + i) * PLANE + p128];
    #pragma unroll
    for (int i = 0; i < 16; ++i) sB[i] = xrow[(size_t)(32 + i) * PLANE + p128];
    __syncthreads();

#define MFMA_SEC(c, cb)                                                     \
    __builtin_amdgcn_sched_barrier(0);                                      \
    _Pragma("unroll")                                                       \
    for (int tap = 0; tap < 9; ++tap) {                                     \
        const int dy = tap / 3;                                             \
        const int dx = tap % 3 - 1;                                         \
        const int slot = out_row + dy;                                      \
        const int apx  = px_tile + m + 1 + dx;                              \
        bf16x8 a = *(const bf16x8*)(lds + lds_off(cb, slot, apx, hi * 8));  \
        bf16x8 b = *(const bf16x8*)(wB +                                    \
            (((size_t)tap * 32 + h * 16 + (c) * 2 + hi) * 32 + m) * 8);     \
        acc = __builtin_amdgcn_mfma_f32_32x32x16_bf16(b, a, acc, 0, 0, 0);  \
    }                                                                       \
    __builtin_amdgcn_sched_barrier(0);

#define PACK_SEC(S, tb)                                                     \
    {                                                                       \
        int4 d0 = pack8(&S[0]), d1 = pack8(&S[8]);                          \
        *(int4*)(lds + lds_off(tb, team, p128 + 1, 0)) = d0;                \
        *(int4*)(lds + lds_off(tb, team, p128 + 1, 8)) = d1;                \
        if (p128 == 1) {                                                    \
            *(int4*)(lds + lds_off(tb, team, 0, 0)) = d0;                   \
            *(int4*)(lds + lds_off(tb, team, 0, 8)) = d1;                   \
        }                                                                   \
        if (p128 == 126) {                                                  \
            *(int4*)(lds + lds_off(tb, team, 129, 0)) = d0;                 \
            *(int4*)(lds + lds_off(tb, team, 129, 8)) = d1;                 \
        }                                                                   \
    }

#define ISSUE_SEC(S, k)                                                     \
    _Pragma("unroll")                                                       \
    for (int i = 0; i < 16; ++i)                                            \
        S[i] = xrow[(size_t)((k) * 16 + i) * PLANE + p128];

    #pragma unroll
    for (int cc = 0; cc < 8; cc += 2) {
        // even chunk cc: compute buf0; pack sA (chunk cc+1) -> buf1;
        // refill sA <- chunk cc+3
        MFMA_SEC(cc, 0)
        if (cc < 7) PACK_SEC(sA, 1)
        if (cc + 3 < 8) ISSUE_SEC(sA, cc + 3)
        __syncthreads();
        // odd chunk cc+1: compute buf1; pack sB (chunk cc+2) -> buf0;
        // refill sB <- chunk cc+4
        MFMA_SEC(cc + 1, 1)
        if (cc + 1 < 7) PACK_SEC(sB, 0)
        if (cc + 4 < 8) ISSUE_SEC(sB, cc + 4)
        __syncthreads();
    }
#undef MFMA_SEC
#undef PACK_SEC
#undef ISSUE_SEC

    // ---- epilogue: raw partial store [h][n][oc][y][px] ----
    // C/D layout: col(px)=lane&31, row(oc)=(r&3)+8*(r>>2)+4*hi
    float* po = partial + ((size_t)(h * 8 + n) * NOC) * PLANE
              + (size_t)(y0 + out_row) * HW + px_tile + m;
    #pragma unroll
    for (int r = 0; r < 16; ++r) {
        int oc = (r & 3) + 8 * (r >> 2) + 4 * hi;
        if (oc < NOC) po[(size_t)oc * PLANE] = acc[r];
    }
}

// ------------- Kernel A2: reduce halves + BN + softmax (R12 exact) ---------
__global__ __launch_bounds__(128) void pasa_reduce_softmax(
    const float* __restrict__ partial,
    const float* __restrict__ gamma, const float* __restrict__ beta,
    const float* __restrict__ rmean, const float* __restrict__ rvar,
    float* __restrict__ sigma)
{
    int flat = blockIdx.x;                   // [0,1024)
    int nf   = (flat & 7) * 128 + (flat >> 3);
    const int n = nf >> 7;
    const int y = nf & 127;
    const int px = threadIdx.x;

    const size_t off = (size_t)y * HW + px;
    const float* p0 = partial + ((size_t)n * NOC) * PLANE + off;
    const float* p1 = partial + ((size_t)(8 + n) * NOC) * PLANE + off;

    float vals[NOC];
    float mx = -3.0e38f;
    #pragma unroll
    for (int oc = 0; oc < NOC; ++oc) {
        float s  = p0[(size_t)oc * PLANE] + p1[(size_t)oc * PLANE];
        float sc = gamma[oc] * rsqrtf(rvar[oc] + EPSBN);
        float b  = beta[oc] - rmean[oc] * sc;
        float t  = fmaf(s, sc, b);
        vals[oc] = t;
        mx = fmaxf(mx, t);
    }
    float ssum = 0.0f;
    #pragma unroll
    for (int oc = 0; oc < NOC; ++oc) { vals[oc] = __expf(vals[oc] - mx); ssum += vals[oc]; }
    const float inv = 1.0f / ssum;

    float* so = sigma + (size_t)n * NOC * PLANE + off;
    #pragma unroll
    for (int oc = 0; oc < NOC; ++oc)
        so[(size_t)oc * PLANE] = vals[oc] * inv;
}

// ------------- Kernel B: shuffle-halo pooling (R16 exact) ------------------
__global__ __launch_bounds__(256, 4) void pasa_pool(
    const float* __restrict__ x, const float* __restrict__ sigma,
    float* __restrict__ out)
{
    int flat = blockIdx.x;                 // [0,2048)
    int nf   = (flat & 7) * 256 + (flat >> 3);   // XCD owns one image
    const int n  = nf >> 8;
    const int cs = nf & 15;                // channel slice (16 ch)
    const int yt = (nf >> 4) & 15;         // y-tile (8 rows)

    const int lane = threadIdx.x & 63;
    const int col  = lane & 31;            // px quad in row
    const int rs   = threadIdx.x >> 5;     // row slot 0..7

    const int y   = yt * 8 + rs;
    const int px0 = col * 4;
    const int ym  = (y == 0)      ? 1      : y - 1;
    const int yp  = (y == HW - 1) ? HW - 2 : y + 1;
    const int g   = cs >> 3;               // softmax group

    const float* sg = sigma + ((size_t)n * NOC + g * 9) * PLANE
                            + (size_t)y * HW + px0;
    float sgv[9][4];
    #pragma unroll
    for (int k = 0; k < 9; ++k) {
        float4 t = *(const float4*)(sg + (size_t)k * PLANE);
        sgv[k][0] = t.x; sgv[k][1] = t.y; sgv[k][2] = t.z; sgv[k][3] = t.w;
    }

    const int c0 = cs * 16;
    const float* xn = x + (size_t)n * NCH * PLANE;
    float*       on = out + (size_t)n * NCH * PLANE;

    const size_t ymO = (size_t)ym * HW + px0;
    const size_t yO  = (size_t)y  * HW + px0;
    const size_t ypO = (size_t)yp * HW + px0;

    for (int cc = 0; cc < 16; ++cc) {
        const int c = c0 + cc;
        const float* xc = xn + (size_t)c * PLANE;
        float4 a = *(const float4*)(xc + ymO);
        float4 b = *(const float4*)(xc + yO);
        float4 d = *(const float4*)(xc + ypO);

        float la = __shfl(a.w, lane - 1); if (col == 0)  la = a.y;
        float lb = __shfl(b.w, lane - 1); if (col == 0)  lb = b.y;
        float ld = __shfl(d.w, lane - 1); if (col == 0)  ld = d.y;
        float ra = __shfl(a.x, lane + 1); if (col == 31) ra = a.z;
        float rb = __shfl(b.x, lane + 1); if (col == 31) rb = b.z;
        float rd = __shfl(d.x, lane + 1); if (col == 31) rd = d.z;

        float ov[4] = {0.f, 0.f, 0.f, 0.f};
        {
            float wv[6] = { la, a.x, a.y, a.z, a.w, ra };
            #pragma unroll
            for (int j = 0; j < 4; ++j)
                #pragma unroll
                for (int dx = 0; dx < 3; ++dx)
                    ov[j] = fmaf(wv[j + dx], sgv[dx][j], ov[j]);
        }
        {
            float wv[6] = { lb, b.x, b.y, b.z, b.w, rb };
            #pragma unroll
            for (int j = 0; j < 4; ++j)
                #pragma unroll
                for (int dx = 0; dx < 3; ++dx)
                    ov[j] = fmaf(wv[j + dx], sgv[3 + dx][j], ov[j]);
        }
        {
            float wv[6] = { ld, d.x, d.y, d.z, d.w, rd };
            #pragma unroll
            for (int j = 0; j < 4; ++j)
                #pragma unroll
                for (int dx = 0; dx < 3; ++dx)
                    ov[j] = fmaf(wv[j + dx], sgv[6 + dx][j], ov[j]);
        }
        float4 o4 = { ov[0], ov[1], ov[2], ov[3] };
        *(float4*)(on + (size_t)c * PLANE + yO) = o4;
    }
}

extern "C" void kernel_launch(void* const* d_in, const int* in_sizes, int n_in,
                              void* d_out, int out_size, void* d_ws, size_t ws_size,
                              hipStream_t stream) {
    const float* x     = (const float*)d_in[0];
    const float* w     = (const float*)d_in[1];
    const float* gamma = (const float*)d_in[2];
    const float* beta  = (const float*)d_in[3];
    const float* rmean = (const float*)d_in[4];
    const float* rvar  = (const float*)d_in[5];
    float* out   = (float*)d_out;
    float* sigma = (float*)d_ws;                 // 8*18*16384*4 = 9.44 MB

    // scratch in d_out (pool fully overwrites d_out last):
    //   partial: 2*8*18*16384 fp32 = 18.9 MB at offset 0
    //   wB:      147 KB at float-offset 16M (64 MB)
    float* partial = out;
    unsigned short* wB = (unsigned short*)(out + (size_t)16 * 1024 * 1024);

    pasa_wprep<<<dim3(288), dim3(256), 0, stream>>>(w, wB);
    pasa_conv_part<<<dim3(1024), dim3(512), 0, stream>>>(x, wB, partial);
    pasa_reduce_softmax<<<dim3(1024), dim3(128), 0, stream>>>(
        partial, gamma, beta, rmean, rvar, sigma);
    pasa_pool<<<dim3(2048), dim3(256), 0, stream>>>(x, sigma, out);
}

// Round 22
// 97.683 us; speedup vs baseline: 1.0420x; 1.0420x over previous
//
#include <hip/hip_runtime.h>
#include <cstdint>

#define HW  128
#define NCH 256
#define NOC 18      // G*K*K
#define PLANE (HW * HW)
#define EPSBN 1e-5f

typedef __attribute__((ext_vector_type(8)))  short bf16x8;
typedef __attribute__((ext_vector_type(16))) float f32x16;

__device__ __forceinline__ unsigned short f2bf(float f) {
    union { float f; uint32_t u; } c; c.f = f;
    uint32_t u = c.u;
    uint32_t r = u + 0x7FFFu + ((u >> 16) & 1u);   // RNE
    return (unsigned short)(r >> 16);
}

__device__ __forceinline__ int4 pack8(const float* v) {
    int4 d;
    d.x = (uint32_t)f2bf(v[0]) | ((uint32_t)f2bf(v[1]) << 16);
    d.y = (uint32_t)f2bf(v[2]) | ((uint32_t)f2bf(v[3]) << 16);
    d.z = (uint32_t)f2bf(v[4]) | ((uint32_t)f2bf(v[5]) << 16);
    d.w = (uint32_t)f2bf(v[6]) | ((uint32_t)f2bf(v[7]) << 16);
    return d;
}

// double-buffered swizzled LDS: [buf(2)][slot(4)][px(130)][ic(16)] bf16
// = 33280 B total. px stride 32 B; XOR px bit2 into byte bit4.
__device__ __forceinline__ int lds_off(int buf, int slot, int px, int ic) {
    int b = ((((buf << 2) + slot) * 130 + px) * 16 + ic) * 2;
    return b ^ (((px >> 2) & 1) << 4);
}

// ------------- Kernel W: pack weights -> wB[tap][ic>>3][oc(32 pad)][ic&7] bf16
__global__ __launch_bounds__(256) void pasa_wprep(
    const float* __restrict__ w, unsigned short* __restrict__ wB)
{
    int idx = blockIdx.x * 256 + threadIdx.x;      // 9*32*32*8 = 73728
    int icl = idx & 7;
    int oc  = (idx >> 3) & 31;
    int icb = (idx >> 8) & 31;
    int tap = idx >> 13;
    int ic  = icb * 8 + icl;
    float v = (oc < NOC) ? w[((size_t)oc * NCH + ic) * 9 + tap] : 0.0f;
    wB[idx] = f2bf(v);
}

// ------------- Kernel A: K-split dbuf conv, chunk=16 (R19 best) ------------
// grid 1024 = 8 n x 2 K-halves x 64 row-pairs; 512 thr = 8 waves, (512,4).
// Per chunk: [16 loads/thread for c+1] [9 MFMA on c] [pack+write buf^1]
// [barrier]; 8 chunks per K-half. Writes raw fp32 partials [h][n][oc][y][px].
__global__ __launch_bounds__(512, 4) void pasa_conv_part(
    const float* __restrict__ x, const unsigned short* __restrict__ wB,
    float* __restrict__ partial)
{
    __shared__ __align__(16) char lds[2 * 4 * 130 * 16 * 2];   // 33280 B

    int flat = blockIdx.x;                 // [0,1024)
    const int n     = flat & 7;            // XCD owns one image
    const int local = flat >> 3;           // [0,128)
    const int h     = local >> 6;          // K-half
    const int y0    = (local & 63) * 2;

    const int tid  = threadIdx.x;
    const int lane = tid & 63;
    const int wv   = tid >> 6;             // wave 0..7
    const int m    = lane & 31;            // MFMA col (pixel in tile)
    const int hi   = lane >> 5;            // k-half selector

    const int team = tid >> 7;             // 0..3 -> LDS row slot
    const int p128 = tid & 127;            // global px staged by this thread
    int grow;                              // staged row (reflect)
    if      (team == 0) grow = (y0 == 0) ? 1 : y0 - 1;
    else if (team == 1) grow = y0;
    else if (team == 2) grow = y0 + 1;
    else                grow = (y0 + 1 == HW - 1) ? HW - 2 : y0 + 2;

    const float* xrow = x + (size_t)n * NCH * PLANE
                      + (size_t)(h * 128) * PLANE + (size_t)grow * HW;

    const int out_row = wv >> 2;
    const int px_tile = (wv & 3) * 32;

    f32x16 acc;
    #pragma unroll
    for (int i = 0; i < 16; ++i) acc[i] = 0.0f;

    // ---- prologue: stage chunk 0 into buf 0 ----
    {
        float s0[8], s1[8];
        #pragma unroll
        for (int i = 0; i < 8; ++i) s0[i] = xrow[(size_t)(i)     * PLANE + p128];
        #pragma unroll
        for (int i = 0; i < 8; ++i) s1[i] = xrow[(size_t)(8 + i) * PLANE + p128];
        int4 d0 = pack8(s0), d1 = pack8(s1);
        *(int4*)(lds + lds_off(0, team, p128 + 1, 0)) = d0;
        *(int4*)(lds + lds_off(0, team, p128 + 1, 8)) = d1;
        if (p128 == 1) {
            *(int4*)(lds + lds_off(0, team, 0, 0)) = d0;
            *(int4*)(lds + lds_off(0, team, 0, 8)) = d1;
        }
        if (p128 == 126) {
            *(int4*)(lds + lds_off(0, team, 129, 0)) = d0;
            *(int4*)(lds + lds_off(0, team, 129, 8)) = d1;
        }
    }
    __syncthreads();

    for (int c = 0; c < 8; ++c) {
        const int cb = c & 1;
        const bool more = (c < 7);
        // ---- issue next chunk's loads (fly under the MFMAs) ----
        float s0[8], s1[8];
        if (more) {
            const int icg = (c + 1) * 16;
            #pragma unroll
            for (int i = 0; i < 8; ++i) s0[i] = xrow[(size_t)(icg + i)     * PLANE + p128];
            #pragma unroll
            for (int i = 0; i < 8; ++i) s1[i] = xrow[(size_t)(icg + 8 + i) * PLANE + p128];
        }
        // ---- MFMA: 9 taps x K=16 on chunk c ----
        #pragma unroll
        for (int tap = 0; tap < 9; ++tap) {
            const int dy = tap / 3;
            const int dx = tap % 3 - 1;
            const int slot = out_row + dy;
            const int apx  = px_tile + m + 1 + dx;
            bf16x8 a = *(const bf16x8*)(lds + lds_off(cb, slot, apx, hi * 8));
            bf16x8 b = *(const bf16x8*)(wB +
                (((size_t)tap * 32 + h * 16 + c * 2 + hi) * 32 + m) * 8);
            acc = __builtin_amdgcn_mfma_f32_32x32x16_bf16(b, a, acc, 0, 0, 0);
        }
        // ---- pack + write next chunk into the other buffer ----
        if (more) {
            const int tb = cb ^ 1;
            int4 d0 = pack8(s0), d1 = pack8(s1);
            *(int4*)(lds + lds_off(tb, team, p128 + 1, 0)) = d0;
            *(int4*)(lds + lds_off(tb, team, p128 + 1, 8)) = d1;
            if (p128 == 1) {
                *(int4*)(lds + lds_off(tb, team, 0, 0)) = d0;
                *(int4*)(lds + lds_off(tb, team, 0, 8)) = d1;
            }
            if (p128 == 126) {
                *(int4*)(lds + lds_off(tb, team, 129, 0)) = d0;
                *(int4*)(lds + lds_off(tb, team, 129, 8)) = d1;
            }
        }
        __syncthreads();
    }

    // ---- epilogue: raw partial store [h][n][oc][y][px] ----
    // C/D layout: col(px)=lane&31, row(oc)=(r&3)+8*(r>>2)+4*hi
    float* po = partial + ((size_t)(h * 8 + n) * NOC) * PLANE
              + (size_t)(y0 + out_row) * HW + px_tile + m;
    #pragma unroll
    for (int r = 0; r < 16; ++r) {
        int oc = (r & 3) + 8 * (r >> 2) + 4 * hi;
        if (oc < NOC) po[(size_t)oc * PLANE] = acc[r];
    }
}

// ------------- Kernel A2: reduce halves + BN + softmax (R12 exact) ---------
__global__ __launch_bounds__(128) void pasa_reduce_softmax(
    const float* __restrict__ partial,
    const float* __restrict__ gamma, const float* __restrict__ beta,
    const float* __restrict__ rmean, const float* __restrict__ rvar,
    float* __restrict__ sigma)
{
    int flat = blockIdx.x;                   // [0,1024)
    int nf   = (flat & 7) * 128 + (flat >> 3);
    const int n = nf >> 7;
    const int y = nf & 127;
    const int px = threadIdx.x;

    const size_t off = (size_t)y * HW + px;
    const float* p0 = partial + ((size_t)n * NOC) * PLANE + off;
    const float* p1 = partial + ((size_t)(8 + n) * NOC) * PLANE + off;

    float vals[NOC];
    float mx = -3.0e38f;
    #pragma unroll
    for (int oc = 0; oc < NOC; ++oc) {
        float s  = p0[(size_t)oc * PLANE] + p1[(size_t)oc * PLANE];
        float sc = gamma[oc] * rsqrtf(rvar[oc] + EPSBN);
        float b  = beta[oc] - rmean[oc] * sc;
        float t  = fmaf(s, sc, b);
        vals[oc] = t;
        mx = fmaxf(mx, t);
    }
    float ssum = 0.0f;
    #pragma unroll
    for (int oc = 0; oc < NOC; ++oc) { vals[oc] = __expf(vals[oc] - mx); ssum += vals[oc]; }
    const float inv = 1.0f / ssum;

    float* so = sigma + (size_t)n * NOC * PLANE + off;
    #pragma unroll
    for (int oc = 0; oc < NOC; ++oc)
        so[(size_t)oc * PLANE] = vals[oc] * inv;
}

// ------------- Kernel B: shuffle-halo pooling (R16 exact) ------------------
__global__ __launch_bounds__(256, 4) void pasa_pool(
    const float* __restrict__ x, const float* __restrict__ sigma,
    float* __restrict__ out)
{
    int flat = blockIdx.x;                 // [0,2048)
    int nf   = (flat & 7) * 256 + (flat >> 3);   // XCD owns one image
    const int n  = nf >> 8;
    const int cs = nf & 15;                // channel slice (16 ch)
    const int yt = (nf >> 4) & 15;         // y-tile (8 rows)

    const int lane = threadIdx.x & 63;
    const int col  = lane & 31;            // px quad in row
    const int rs   = threadIdx.x >> 5;     // row slot 0..7

    const int y   = yt * 8 + rs;
    const int px0 = col * 4;
    const int ym  = (y == 0)      ? 1      : y - 1;
    const int yp  = (y == HW - 1) ? HW - 2 : y + 1;
    const int g   = cs >> 3;               // softmax group

    const float* sg = sigma + ((size_t)n * NOC + g * 9) * PLANE
                            + (size_t)y * HW + px0;
    float sgv[9][4];
    #pragma unroll
    for (int k = 0; k < 9; ++k) {
        float4 t = *(const float4*)(sg + (size_t)k * PLANE);
        sgv[k][0] = t.x; sgv[k][1] = t.y; sgv[k][2] = t.z; sgv[k][3] = t.w;
    }

    const int c0 = cs * 16;
    const float* xn = x + (size_t)n * NCH * PLANE;
    float*       on = out + (size_t)n * NCH * PLANE;

    const size_t ymO = (size_t)ym * HW + px0;
    const size_t yO  = (size_t)y  * HW + px0;
    const size_t ypO = (size_t)yp * HW + px0;

    for (int cc = 0; cc < 16; ++cc) {
        const int c = c0 + cc;
        const float* xc = xn + (size_t)c * PLANE;
        float4 a = *(const float4*)(xc + ymO);
        float4 b = *(const float4*)(xc + yO);
        float4 d = *(const float4*)(xc + ypO);

        float la = __shfl(a.w, lane - 1); if (col == 0)  la = a.y;
        float lb = __shfl(b.w, lane - 1); if (col == 0)  lb = b.y;
        float ld = __shfl(d.w, lane - 1); if (col == 0)  ld = d.y;
        float ra = __shfl(a.x, lane + 1); if (col == 31) ra = a.z;
        float rb = __shfl(b.x, lane + 1); if (col == 31) rb = b.z;
        float rd = __shfl(d.x, lane + 1); if (col == 31) rd = d.z;

        float ov[4] = {0.f, 0.f, 0.f, 0.f};
        {
            float wv[6] = { la, a.x, a.y, a.z, a.w, ra };
            #pragma unroll
            for (int j = 0; j < 4; ++j)
                #pragma unroll
                for (int dx = 0; dx < 3; ++dx)
                    ov[j] = fmaf(wv[j + dx], sgv[dx][j], ov[j]);
        }
        {
            float wv[6] = { lb, b.x, b.y, b.z, b.w, rb };
            #pragma unroll
            for (int j = 0; j < 4; ++j)
                #pragma unroll
                for (int dx = 0; dx < 3; ++dx)
                    ov[j] = fmaf(wv[j + dx], sgv[3 + dx][j], ov[j]);
        }
        {
            float wv[6] = { ld, d.x, d.y, d.z, d.w, rd };
            #pragma unroll
            for (int j = 0; j < 4; ++j)
                #pragma unroll
                for (int dx = 0; dx < 3; ++dx)
                    ov[j] = fmaf(wv[j + dx], sgv[6 + dx][j], ov[j]);
        }
        float4 o4 = { ov[0], ov[1], ov[2], ov[3] };
        *(float4*)(on + (size_t)c * PLANE + yO) = o4;
    }
}

extern "C" void kernel_launch(void* const* d_in, const int* in_sizes, int n_in,
                              void* d_out, int out_size, void* d_ws, size_t ws_size,
                              hipStream_t stream) {
    const float* x     = (const float*)d_in[0];
    const float* w     = (const float*)d_in[1];
    const float* gamma = (const float*)d_in[2];
    const float* beta  = (const float*)d_in[3];
    const float* rmean = (const float*)d_in[4];
    const float* rvar  = (const float*)d_in[5];
    float* out   = (float*)d_out;
    float* sigma = (float*)d_ws;                 // 8*18*16384*4 = 9.44 MB

    // scratch in d_out (pool fully overwrites d_out last):
    //   partial: 2*8*18*16384 fp32 = 18.9 MB at offset 0
    //   wB:      147 KB at float-offset 16M (64 MB)
    float* partial = out;
    unsigned short* wB = (unsigned short*)(out + (size_t)16 * 1024 * 1024);

    pasa_wprep<<<dim3(288), dim3(256), 0, stream>>>(w, wB);
    pasa_conv_part<<<dim3(1024), dim3(512), 0, stream>>>(x, wB, partial);
    pasa_reduce_softmax<<<dim3(1024), dim3(128), 0, stream>>>(
        partial, gamma, beta, rmean, rvar, sigma);
    pasa_pool<<<dim3(2048), dim3(256), 0, stream>>>(x, sigma, out);
}